// Round 8
// baseline (3914.487 us; speedup 1.0000x reference)
//
#include <hip/hip_runtime.h>
#include <hip/hip_bf16.h>
#include <stdint.h>
#include <string.h>

// ---------------- problem constants ----------------
// B=64, T=256, D=H=256, L=50, O=2; K = 2H = 512 (concat [h_in; h_prev]); G = 4H = 1024
#define NB   64
#define NT   256
#define NH   256
#define NL   50
#define NK   512
#define NG   1024

typedef __attribute__((ext_vector_type(8)))  short   short8;
typedef __attribute__((ext_vector_type(8)))  __bf16  bf16x8;
typedef __attribute__((ext_vector_type(4)))  float   float4v;

__device__ __forceinline__ unsigned short f2bf(float f) {
  union { float f; uint32_t u; } v; v.f = f;
  uint32_t u = v.u;
  uint32_t r = (u + 0x7FFFu + ((u >> 16) & 1u)) >> 16;   // RNE
  return (unsigned short)r;
}
__device__ __forceinline__ float bf2f(unsigned short s) {
  union { uint32_t u; float f; } v; v.u = ((uint32_t)s) << 16;
  return v.f;
}
// fast, overflow-safe activations (tolerance 1e-2; v_exp/v_rcp ~1ulp)
__device__ __forceinline__ float sigmoid_f(float x) {
  return 1.0f / (1.0f + __expf(-x));
}
__device__ __forceinline__ float tanh_f(float x) {
  float e = __expf(-2.0f * __builtin_fabsf(x));   // in (0,1]
  float r = (1.0f - e) / (1.0f + e);
  return __builtin_copysignf(r, x);
}

// ---- coherent ops (sc1 = agent scope / LLC coherence point; mechanism
// validated R5-R7: ordering via per-wave s_waitcnt vmcnt(0), no fences) ----
__device__ __forceinline__ short8 ldg_sc1_b128(const unsigned short* p) {
  short8 r;
  asm volatile("global_load_dwordx4 %0, %1, off sc1" : "=v"(r) : "v"(p) : "memory");
  return r;
}
__device__ __forceinline__ void stg_sc1_b16(unsigned short* p, int v) {
  asm volatile("global_store_short %0, %1, off sc1" :: "v"(p), "v"(v) : "memory");
}
__device__ __forceinline__ void wait_vm0() {
  asm volatile("s_waitcnt vmcnt(0)" ::: "memory");
}
// poll 16 per-chunk flags: lane i loads flag i&15 (one 64B coalesced txn),
// ballot-combine; s_sleep backoff keeps the LLC line cool.
__device__ __forceinline__ void wave_wait16(const int* p, int ln) {
  const int* a = p + (ln & 15);
  for (;;) {
    int f;
    asm volatile("global_load_dword %0, %1, off sc1\n\ts_waitcnt vmcnt(0)"
                 : "=v"(f) : "v"(a) : "memory");
    if (__ballot(f != 0) == ~0ull) break;
    __builtin_amdgcn_s_sleep(1);
  }
}
// poll 4 per-WG cons flags (lane i reads i&3; one 16B txn)
__device__ __forceinline__ void wave_wait4(const int* p, int ln) {
  const int* a = p + (ln & 3);
  for (;;) {
    int f;
    asm volatile("global_load_dword %0, %1, off sc1\n\ts_waitcnt vmcnt(0)"
                 : "=v"(f) : "v"(a) : "memory");
    if (__ballot(f != 0) == ~0ull) break;
    __builtin_amdgcn_s_sleep(1);
  }
}

// ---------------- workspace layout (bytes) ----------------
// Wswz 52,428,800 | Bias 204,800 | Xbf 8,388,608 | Hring(4 slots) 6,553,600 |
// Y 8,388,608 | prod16 50*256*16*4 = 819,200 | cons4 50*256*4*4 = 204,800
#define OFF_WSWZ  0
#define OFF_BIAS  52428800
#define OFF_XBF   52633600
#define OFF_HRING 61022208
#define OFF_Y     67575808
#define OFF_PROD  75964416
#define OFF_CONS  76783616
// total: 76,988,416 bytes

// ---------------- preprocessing ----------------
// Weight swizzle: Wswz[idx], idx = ((((l*16+c)*4+q)*16+kt)*64+lam)*8+j
// holds Wcat[g = q*256 + c*16 + (lam&15)][k = kt*32 + (lam>>4)*8 + j] as bf16.
// Exact MFMA B-fragment lane order (verified R1-R7).
__global__ void prep_w(const float* __restrict__ Wih, const float* __restrict__ Whh,
                       unsigned short* __restrict__ Wswz) {
  int idx = blockIdx.x * 256 + threadIdx.x;        // 26,214,400 total
  int j   = idx & 7;
  int lam = (idx >> 3) & 63;
  int kt  = (idx >> 9) & 15;
  int q   = (idx >> 13) & 3;
  int c   = (idx >> 15) & 15;
  int l   = idx >> 19;
  int k   = kt * 32 + (lam >> 4) * 8 + j;
  int g   = q * 256 + c * 16 + (lam & 15);
  float v = (k < 256) ? Wih[(l * NG + g) * 256 + k]
                      : Whh[(l * NG + g) * 256 + (k - 256)];
  Wswz[idx] = f2bf(v);
}

__global__ void prep_bias(const float* __restrict__ bih, const float* __restrict__ bhh,
                          float* __restrict__ Bias) {
  int idx = blockIdx.x * 256 + threadIdx.x;        // 51,200 total
  int col = idx & 15; int q = (idx >> 4) & 3; int c = (idx >> 6) & 15; int l = idx >> 10;
  int g = q * 256 + c * 16 + col;
  Bias[idx] = bih[l * NG + g] + bhh[l * NG + g];
}

__global__ void prep_x(const float* __restrict__ x, unsigned short* __restrict__ Xbf) {
  int idx = blockIdx.x * 256 + threadIdx.x;        // 4,194,304 total
  int d = idx & 255; int t = (idx >> 8) & 255; int b = idx >> 16;
  Xbf[(t * NB + b) * 256 + d] = f2bf(x[idx]);
}

__global__ void zero_flags(int* __restrict__ p) {
  p[blockIdx.x * 256 + threadIdx.x] = 0;           // 256,000 ints (prod16+cons4)
}

// ---------------- persistent LSTM kernel ----------------
// Grid 256 (56 exit): x=blockIdx&7 ~ XCD locality heuristic (never correctness).
// 83KB LDS + 256 VGPR/wave force 1 WG/CU -> all 200 workers co-resident; each
// wave's 64KB weight chunk register-resident for all 256 timesteps.
// Per-beat structure (2 barriers): [per-wave flag waits + staging loads] ->
// B1 (joins prev GEMM readers) -> LDS writes -> B2 -> GEMM -> per-wave
// epilogue: direct 2B sc1 stores from acc regs -> own vmcnt(0) -> per-chunk
// flag store. Consumers poll 16 chunk flags with one 64B coalesced load.
#define RSTRIDE 81   // LDS row stride in 16B units; 81 % 8 == 1 -> conflict-free
__global__ __launch_bounds__(256, 1) void lstm_persistent(
    const unsigned short* __restrict__ Wswz,
    const float* __restrict__ Bias,
    const unsigned short* __restrict__ Xbf,
    unsigned short* __restrict__ Hring,
    unsigned short* __restrict__ Y,
    int* __restrict__ prod16,
    int* __restrict__ cons4) {
  int xcd = blockIdx.x & 7;
  int jj  = blockIdx.x >> 3;
  int l   = xcd * 7 + (jj >> 2);
  int w   = jj & 3;
  if (jj >= 28 || l >= NL) return;     // 56 idle WGs exit
  int tid = threadIdx.x;

  __shared__ unsigned short hc[64 * RSTRIDE * 8];     // 82,944 B staging

  int wv   = tid >> 6;              // wave 0..3
  int ln   = tid & 63;
  int c    = w * 4 + wv;            // gate chunk 0..15 -> hidden units [c*16, c*16+16)
  int colg = ln & 15;
  int quad = ln >> 4;
  bool pvside = (wv & 1);           // staging: odd waves load h_prev half
  int  brb    = wv >> 1;            // staging row-group parity

  // ---- one-time: weights into registers (64 x bf16x8 = 256 VGPRs/lane) ----
  bf16x8 wreg[64];
  {
    const unsigned short* wp = Wswz + (size_t)(l * 16 + c) * 32768 + ln * 8;
#pragma unroll
    for (int i = 0; i < 64; ++i)
      wreg[i] = *(const bf16x8*)(wp + i * 512);
  }
  float bv[4];
  {
    const float* bp = Bias + l * NG + c * 64;
#pragma unroll
    for (int q = 0; q < 4; ++q) bv[q] = bp[q * 16 + colg];
  }

  float cr[4][4] = {};              // cell state in registers
  int j = c * 16 + colg;
  bool last = (l == NL - 1);

  for (int t = 0; t < NT; ++t) {
    // ---- per-wave dependency gate + coalesced staging loads (pre-barrier:
    // overlaps sibling waves' tail of beat t-1) ----
    short8 v[16];
    {
      int e  = ln & 31;             // 16B unit within a 512B half-row
      int rs = ln >> 5;             // row parity within the pair
      if (!pvside) {
        if (l > 0) {
          wave_wait16(&prod16[((l - 1) * NT + t) * 16], ln);
          const unsigned short* In = Hring + (((t & 3) * NL + (l - 1)) * NB) * 256;
#pragma unroll
          for (int i = 0; i < 16; ++i) {
            int b = i * 4 + brb * 2 + rs;
            v[i] = ldg_sc1_b128(In + b * 256 + e * 8);
          }
        } else {
          const unsigned short* In = Xbf + t * (NB * 256);   // read-only: plain cached loads
#pragma unroll
          for (int i = 0; i < 16; ++i) {
            int b = i * 4 + brb * 2 + rs;
            v[i] = *(const short8*)(In + b * 256 + e * 8);
          }
        }
      } else if (t > 0) {
        wave_wait16(&prod16[(l * NT + (t - 1)) * 16], ln);
        const unsigned short* Pv = Hring + ((((t - 1) & 3) * NL + l) * NB) * 256;
#pragma unroll
        for (int i = 0; i < 16; ++i) {
          int b = i * 4 + brb * 2 + rs;
          v[i] = ldg_sc1_b128(Pv + b * 256 + e * 8);
        }
      } else {
#pragma unroll
        for (int i = 0; i < 16; ++i) v[i] = short8{0, 0, 0, 0, 0, 0, 0, 0};
      }
      wait_vm0();                   // loads landed in regs
    }
    __syncthreads();                // B1: all waves past their beat-(t-1) hc reads
    {
      int e  = ln & 31;
      int rs = ln >> 5;
      int kb = (pvside ? 32 : 0) + e;
#pragma unroll
      for (int i = 0; i < 16; ++i) {
        int b = i * 4 + brb * 2 + rs;
        *(short8*)(hc + (b * RSTRIDE + kb) * 8) = v[i];
      }
    }
    __syncthreads();                // B2: staging visible to all waves
    if (tid == 0 && l > 0)          // upstream ring slot consumed
      __hip_atomic_store(&cons4[((l - 1) * NT + t) * 4 + w], 1,
                         __ATOMIC_RELAXED, __HIP_MEMORY_SCOPE_AGENT);

    // ---- GEMM: 256 MFMAs/wave, weights from registers ----
    float4v acc[4][4];
#pragma unroll
    for (int q = 0; q < 4; ++q) {
      float4v f4 = {bv[q], bv[q], bv[q], bv[q]};
#pragma unroll
      for (int m = 0; m < 4; ++m) acc[m][q] = f4;
    }
#pragma unroll
    for (int kt = 0; kt < 16; ++kt) {
      bf16x8 a[4];
#pragma unroll
      for (int m = 0; m < 4; ++m)
        a[m] = *(const bf16x8*)(hc + ((m * 16 + colg) * RSTRIDE + kt * 4 + quad) * 8);
#pragma unroll
      for (int m = 0; m < 4; ++m)
#pragma unroll
        for (int q = 0; q < 4; ++q)
          acc[m][q] = __builtin_amdgcn_mfma_f32_16x16x32_bf16(a[m], wreg[q * 16 + kt], acc[m][q], 0, 0, 0);
    }

    // ---- ring backpressure (per-wave, usually pre-satisfied) ----
    if (!last && t >= 4) wave_wait4(&cons4[(l * NT + (t - 4)) * 4], ln);

    // ---- epilogue: gates -> c,h ; DIRECT 2B sc1 stores from registers ----
    {
      unsigned short* Hout = Hring + (((t & 3) * NL + l) * NB) * 256;
      unsigned short* Yout = Y + (t * NB) * 256;
#pragma unroll
      for (int m = 0; m < 4; ++m) {
#pragma unroll
        for (int r = 0; r < 4; ++r) {
          int b = m * 16 + quad * 4 + r;
          float gi = sigmoid_f(acc[m][0][r]);
          float gf = sigmoid_f(acc[m][1][r]);
          float gg = tanh_f(acc[m][2][r]);
          float go = sigmoid_f(acc[m][3][r]);
          float cn = gf * cr[m][r] + gi * gg;   // cr starts 0 => t=0 correct
          cr[m][r] = cn;
          float h = go * tanh_f(cn);
          unsigned short hb = f2bf(h);
          stg_sc1_b16(Hout + b * 256 + j, (int)hb);
          if (last) Yout[b * 256 + j] = hb;
        }
      }
      wait_vm0();                   // this wave's 16 columns at coherence point
      if (ln == 0)
        __hip_atomic_store(&prod16[(l * NT + t) * 16 + c], 1,
                           __ATOMIC_RELAXED, __HIP_MEMORY_SCOPE_AGENT);
    }
  }
}

// ---------------- final projection ----------------
__global__ void final_proj(const unsigned short* __restrict__ Y,
                           const float* __restrict__ Wout,
                           const float* __restrict__ bout,
                           float* __restrict__ out) {
  int t = blockIdx.x;
  int tid = threadIdx.x;            // 128 = 64 b * 2 o
  int b = tid >> 1, o = tid & 1;
  const unsigned short* yrow = Y + (t * NB + b) * 256;
  const float* wr = Wout + o * 256;
  float s = bout[o];
  for (int k0 = 0; k0 < 256; k0 += 8) {
    short8 yv = *(const short8*)(yrow + k0);
#pragma unroll
    for (int e = 0; e < 8; ++e)
      s += bf2f(((unsigned short*)&yv)[e]) * wr[k0 + e];
  }
  out[(b * NT + t) * 2 + o] = 1.0f / (1.0f + __expf(-s));
}

extern "C" void kernel_launch(void* const* d_in, const int* in_sizes, int n_in,
                              void* d_out, int out_size, void* d_ws, size_t ws_size,
                              hipStream_t stream) {
  (void)in_sizes; (void)n_in; (void)out_size; (void)ws_size;
  const float* x    = (const float*)d_in[0];
  const float* Wih  = (const float*)d_in[1];
  const float* Whh  = (const float*)d_in[2];
  const float* bih  = (const float*)d_in[3];
  const float* bhh  = (const float*)d_in[4];
  const float* Wout = (const float*)d_in[5];
  const float* bout = (const float*)d_in[6];
  float* out = (float*)d_out;

  char* ws = (char*)d_ws;
  unsigned short* Wswz   = (unsigned short*)(ws + OFF_WSWZ);
  float*          Bias   = (float*)(ws + OFF_BIAS);
  unsigned short* Xbf    = (unsigned short*)(ws + OFF_XBF);
  unsigned short* Hring  = (unsigned short*)(ws + OFF_HRING);
  unsigned short* Y      = (unsigned short*)(ws + OFF_Y);
  int*            prod16 = (int*)(ws + OFF_PROD);
  int*            cons4  = (int*)(ws + OFF_CONS);

  prep_w    <<<102400, 256, 0, stream>>>(Wih, Whh, Wswz);
  prep_bias <<<200,    256, 0, stream>>>(bih, bhh, Bias);
  prep_x    <<<16384,  256, 0, stream>>>(x, Xbf);
  zero_flags<<<1000,   256, 0, stream>>>(prod16);    // prod16+cons4 contiguous

  lstm_persistent<<<256, 256, 0, stream>>>(Wswz, Bias, Xbf, Hring, Y, prod16, cons4);

  final_proj<<<NT, 128, 0, stream>>>(Y, Wout, bout, out);
}